// Round 1
// baseline (902.785 us; speedup 1.0000x reference)
//
#include <hip/hip_runtime.h>

// Problem constants (from reference setup_inputs)
#define BB 4
#define LL 5
#define CC 256
#define HH 100
#define WW 252
#define HW (HH * WW)      // 25200
#define HW4 (HW / 4)      // 6300
#define NPAIR (BB * LL)   // 20
#define KSEL 1024

// ---------------------------------------------------------------------------
// Kernel 1: s[b,l,hw] = sigmoid(max_c(psm[b,l,c,hw] - psm[b,0,c,hw]))
// Cp = 2. Stable two-branch sigmoid to mirror numpy semantics.
// ---------------------------------------------------------------------------
__global__ __launch_bounds__(256) void sig_kernel(const float* __restrict__ psm,
                                                  float* __restrict__ s) {
    int i = blockIdx.x * 256 + threadIdx.x;
    if (i >= NPAIR * HW) return;
    int hw = i % HW;
    int bl = i / HW;
    int b  = bl / LL;
    const float* p  = psm + (size_t)bl * 2 * HW;        // psm[b,l,:,:,:]
    const float* pe = psm + (size_t)(b * LL) * 2 * HW;  // psm[b,0,:,:,:]
    float d0 = p[hw]      - pe[hw];
    float d1 = p[HW + hw] - pe[HW + hw];
    float d  = fmaxf(d0, d1);
    float sv;
    if (d >= 0.0f) {
        sv = 1.0f / (1.0f + expf(-d));
    } else {
        float e = expf(d);
        sv = e / (1.0f + e);
    }
    s[i] = sv;
}

// ---------------------------------------------------------------------------
// Kernel 2: per-(b,l) radix select -> exact K-th largest sigmoid value.
// Keys are positive fp32, so uint bit order == float order. 4 passes of
// 8-bit digits MSB->LSB with an LDS histogram. One 256-thread block per (b,l).
// ---------------------------------------------------------------------------
__global__ __launch_bounds__(256) void select_kernel(const float* __restrict__ s,
                                                     float* __restrict__ thresh) {
    int bl = blockIdx.x;
    const float* base = s + (size_t)bl * HW;
    __shared__ unsigned hist[256];
    __shared__ unsigned sh_prefix;
    __shared__ int sh_k;
    if (threadIdx.x == 0) { sh_prefix = 0u; sh_k = KSEL; }
    __syncthreads();
    for (int sh = 24; sh >= 0; sh -= 8) {
        hist[threadIdx.x] = 0u;
        __syncthreads();
        unsigned prefix = sh_prefix;
        for (int i = threadIdx.x; i < HW; i += 256) {
            unsigned u = __float_as_uint(base[i]);
            bool ok = (sh == 24) || (((u ^ prefix) >> (sh + 8)) == 0u);
            if (ok) atomicAdd(&hist[(u >> sh) & 255u], 1u);
        }
        __syncthreads();
        if (threadIdx.x == 0) {
            int kk = sh_k;
            int bin = 255;
            for (; bin > 0; --bin) {
                int c = (int)hist[bin];
                if (kk - c <= 0) break;
                kk -= c;
            }
            sh_prefix = prefix | ((unsigned)bin << sh);
            sh_k = kk;
        }
        __syncthreads();
    }
    if (threadIdx.x == 0) thresh[bl] = __uint_as_float(sh_prefix);
}

// ---------------------------------------------------------------------------
// Kernel 3: dense output. One float4 per thread, exact grid (no loop).
//   l==0        -> out = x
//   mask[b,l]=0 -> out = 0   (x NOT read)
//   else        -> out_i = (s_i >= t) ? x_i : 0  (x read only if any lane passes)
// ---------------------------------------------------------------------------
__global__ __launch_bounds__(256) void out_kernel(const float* __restrict__ x,
                                                  const int* __restrict__ mask,
                                                  const float* __restrict__ s,
                                                  const float* __restrict__ thresh,
                                                  float* __restrict__ out) {
    int g = blockIdx.x * 256 + threadIdx.x;   // < 32,256,000 : fits in int
    int hw4   = g % HW4;
    int rest  = g / HW4;       // (b*L + l)*C + c
    int rest2 = rest / CC;     // b*L + l
    int l = rest2 % LL;
    int b = rest2 / LL;

    const float4* x4 = (const float4*)x;
    float4* o4 = (float4*)out;
    float4 res;

    if (l == 0) {
        res = x4[g];
    } else if (mask[b * LL + l] == 0) {
        res = make_float4(0.f, 0.f, 0.f, 0.f);
    } else {
        int bl = b * LL + l;
        float t = thresh[bl];
        float4 sv = ((const float4*)(s + (size_t)bl * HW))[hw4];
        bool m0 = sv.x >= t, m1 = sv.y >= t, m2 = sv.z >= t, m3 = sv.w >= t;
        if (m0 | m1 | m2 | m3) {
            float4 xv = x4[g];
            res.x = m0 ? xv.x : 0.f;
            res.y = m1 ? xv.y : 0.f;
            res.z = m2 ? xv.z : 0.f;
            res.w = m3 ? xv.w : 0.f;
        } else {
            res = make_float4(0.f, 0.f, 0.f, 0.f);
        }
    }
    o4[g] = res;
}

// ---------------------------------------------------------------------------
extern "C" void kernel_launch(void* const* d_in, const int* in_sizes, int n_in,
                              void* d_out, int out_size, void* d_ws, size_t ws_size,
                              hipStream_t stream) {
    const float* x   = (const float*)d_in[0];
    const float* psm = (const float*)d_in[1];
    const int* mask  = (const int*)d_in[2];
    float* out = (float*)d_out;

    float* s      = (float*)d_ws;            // NPAIR*HW floats = 2,016,000 B
    float* thresh = s + (size_t)NPAIR * HW;  // 20 floats

    int n_s = NPAIR * HW;
    sig_kernel<<<(n_s + 255) / 256, 256, 0, stream>>>(psm, s);
    select_kernel<<<NPAIR, 256, 0, stream>>>(s, thresh);

    int n4 = BB * LL * CC * HW4;             // 32,256,000
    out_kernel<<<n4 / 256, 256, 0, stream>>>(x, mask, s, thresh, out);
}

// Round 2
// 828.874 us; speedup vs baseline: 1.0892x; 1.0892x over previous
//
#include <hip/hip_runtime.h>

// Problem constants (from reference setup_inputs)
#define BB 4
#define LL 5
#define CC 256
#define HH 100
#define WW 252
#define HW (HH * WW)      // 25200
#define HW4 (HW / 4)      // 6300
#define NPAIR (BB * LL)   // 20
#define KSEL 1024

// ---------------------------------------------------------------------------
// Kernel 1: s[b,l,hw] = sigmoid(max_c(psm[b,l,c,hw] - psm[b,0,c,hw]))
// Cp = 2. Stable two-branch sigmoid to mirror numpy semantics.
// ---------------------------------------------------------------------------
__global__ __launch_bounds__(256) void sig_kernel(const float* __restrict__ psm,
                                                  float* __restrict__ s) {
    int i = blockIdx.x * 256 + threadIdx.x;
    if (i >= NPAIR * HW) return;
    int hw = i % HW;
    int bl = i / HW;
    int b  = bl / LL;
    const float* p  = psm + (size_t)bl * 2 * HW;        // psm[b,l,:,:,:]
    const float* pe = psm + (size_t)(b * LL) * 2 * HW;  // psm[b,0,:,:,:]
    float d0 = p[hw]      - pe[hw];
    float d1 = p[HW + hw] - pe[HW + hw];
    float d  = fmaxf(d0, d1);
    float sv;
    if (d >= 0.0f) {
        sv = 1.0f / (1.0f + expf(-d));
    } else {
        float e = expf(d);
        sv = e / (1.0f + e);
    }
    s[i] = sv;
}

// ---------------------------------------------------------------------------
// Kernel 2: per-(b,l) radix select -> exact K-th largest sigmoid value.
// Keys are positive fp32 (sigmoid output), so uint bit order == float order.
// 4 passes of 8-bit digits MSB->LSB with an LDS histogram.
// 1024 threads/block (16 waves) for latency hiding; one block per (b,l).
// Pairs with l==0 or mask==0 never consume the threshold -> early-out.
// ---------------------------------------------------------------------------
__global__ __launch_bounds__(1024) void select_kernel(const float* __restrict__ s,
                                                      const int* __restrict__ mask,
                                                      float* __restrict__ thresh) {
    int bl = blockIdx.x;
    int l  = bl % LL;
    if (l == 0 || mask[bl] == 0) {
        if (threadIdx.x == 0) thresh[bl] = __int_as_float(0x7f800000); // unused
        return;
    }
    const float* base = s + (size_t)bl * HW;
    __shared__ unsigned hist[256];
    __shared__ unsigned sh_prefix;
    __shared__ int sh_k;
    if (threadIdx.x == 0) { sh_prefix = 0u; sh_k = KSEL; }
    __syncthreads();
    for (int sh = 24; sh >= 0; sh -= 8) {
        if (threadIdx.x < 256) hist[threadIdx.x] = 0u;
        __syncthreads();
        unsigned prefix = sh_prefix;
        for (int i = threadIdx.x; i < HW; i += 1024) {
            unsigned u = __float_as_uint(base[i]);
            bool ok = (sh == 24) || (((u ^ prefix) >> (sh + 8)) == 0u);
            if (ok) atomicAdd(&hist[(u >> sh) & 255u], 1u);
        }
        __syncthreads();
        if (threadIdx.x == 0) {
            int kk = sh_k;
            int bin = 255;
            for (; bin > 0; --bin) {
                int c = (int)hist[bin];
                if (kk - c <= 0) break;
                kk -= c;
            }
            sh_prefix = prefix | ((unsigned)bin << sh);
            sh_k = kk;
        }
        __syncthreads();
    }
    if (threadIdx.x == 0) thresh[bl] = __uint_as_float(sh_prefix);
}

// ---------------------------------------------------------------------------
// Kernel 3: dense output. 3D grid: x covers HW4 (float4 groups), y = channel,
// z = (b*L + l). Branches are block-uniform (no exec-mask divergence on the
// l==0 / mask==0 paths) and there is no per-thread integer division.
//   l==0        -> out = x
//   mask[b,l]=0 -> out = 0   (x NOT read)
//   else        -> out_i = (s_i >= t) ? x_i : 0  (x read only if any lane passes)
// ---------------------------------------------------------------------------
__global__ __launch_bounds__(256) void out_kernel(const float* __restrict__ x,
                                                  const int* __restrict__ mask,
                                                  const float* __restrict__ s,
                                                  const float* __restrict__ thresh,
                                                  float* __restrict__ out) {
    int bl  = blockIdx.z;                       // 0..19
    int c   = blockIdx.y;                       // 0..255
    int hw4 = blockIdx.x * 256 + threadIdx.x;   // 0..6299 (+tail)
    if (hw4 >= HW4) return;
    int l = bl % LL;

    int g = (bl * CC + c) * HW4 + hw4;          // float4-group index, < 2^25
    const float4* x4 = (const float4*)x;
    float4* o4 = (float4*)out;

    if (l == 0) {                               // block-uniform
        o4[g] = x4[g];
        return;
    }
    if (mask[bl] == 0) {                        // block-uniform (scalar load)
        o4[g] = make_float4(0.f, 0.f, 0.f, 0.f);
        return;
    }
    float t = thresh[bl];
    float4 sv = ((const float4*)s)[bl * HW4 + hw4];
    bool m0 = sv.x >= t, m1 = sv.y >= t, m2 = sv.z >= t, m3 = sv.w >= t;
    float4 res;
    if (m0 | m1 | m2 | m3) {
        float4 xv = x4[g];
        res.x = m0 ? xv.x : 0.f;
        res.y = m1 ? xv.y : 0.f;
        res.z = m2 ? xv.z : 0.f;
        res.w = m3 ? xv.w : 0.f;
    } else {
        res = make_float4(0.f, 0.f, 0.f, 0.f);
    }
    o4[g] = res;
}

// ---------------------------------------------------------------------------
extern "C" void kernel_launch(void* const* d_in, const int* in_sizes, int n_in,
                              void* d_out, int out_size, void* d_ws, size_t ws_size,
                              hipStream_t stream) {
    const float* x   = (const float*)d_in[0];
    const float* psm = (const float*)d_in[1];
    const int* mask  = (const int*)d_in[2];
    float* out = (float*)d_out;

    float* s      = (float*)d_ws;            // NPAIR*HW floats = 2,016,000 B
    float* thresh = s + (size_t)NPAIR * HW;  // 20 floats

    int n_s = NPAIR * HW;
    sig_kernel<<<(n_s + 255) / 256, 256, 0, stream>>>(psm, s);
    select_kernel<<<NPAIR, 1024, 0, stream>>>(s, mask, thresh);

    dim3 grid((HW4 + 255) / 256, CC, NPAIR);  // (25, 256, 20)
    out_kernel<<<grid, 256, 0, stream>>>(x, mask, s, thresh, out);
}